// Round 1
// baseline (516.130 us; speedup 1.0000x reference)
//
#include <hip/hip_runtime.h>
#include <hip/hip_bf16.h>

#define NTOK 8192
#define DDIM 1024
#define NEXP 8
#define FDIM 2048
#define NKROW (NTOK * 2)   // 16384 expert-rows (top-2)
#define MAXT 136           // max row-tiles: 16384/128 + 8 rounding

typedef __attribute__((ext_vector_type(8))) short bf16x8;
typedef __attribute__((ext_vector_type(4))) short bf16x4;
typedef __attribute__((ext_vector_type(4))) float f32x4;

__device__ __forceinline__ unsigned short f2bf(float f) {
  union { float f; unsigned u; } v; v.f = f;
  unsigned r = v.u + 0x7fffu + ((v.u >> 16) & 1u);   // RNE
  return (unsigned short)(r >> 16);
}

// ---------------- gate: fp64-accum logits, softmax top-2, renorm ----------------
__global__ void gate_kernel(const float* __restrict__ x, const float* __restrict__ gw,
                            int* __restrict__ tk_e, float* __restrict__ tk_w) {
  int wave = threadIdx.x >> 6, lane = threadIdx.x & 63;
  int n = blockIdx.x * 4 + wave;
  const float* xr = x + (size_t)n * DDIM;
  float xv[16];
#pragma unroll
  for (int i = 0; i < 16; i++) xv[i] = xr[lane + i * 64];
  float lg[NEXP];
#pragma unroll
  for (int e = 0; e < NEXP; e++) {
    const float* gr = gw + e * DDIM;
    double a = 0.0;
#pragma unroll
    for (int i = 0; i < 16; i++) a += (double)xv[i] * (double)gr[lane + i * 64];
#pragma unroll
    for (int s = 32; s > 0; s >>= 1) a += __shfl_xor(a, s, 64);
    lg[e] = (float)a;
  }
  if (lane == 0) {
    int i1 = 0; float b1 = lg[0];
#pragma unroll
    for (int e = 1; e < NEXP; e++) if (lg[e] > b1) { b1 = lg[e]; i1 = e; }
    int i2 = -1; float b2 = -3.4e38f;
#pragma unroll
    for (int e = 0; e < NEXP; e++) if (e != i1 && lg[e] > b2) { b2 = lg[e]; i2 = e; }
    // softmax over all 8 then renorm top-2 == pairwise sigmoid
    float ex = __expf(b2 - b1);
    float inv = 1.0f / (1.0f + ex);
    tk_e[n * 2 + 0] = i1; tk_w[n * 2 + 0] = inv;
    tk_e[n * 2 + 1] = i2; tk_w[n * 2 + 1] = ex * inv;
  }
}

// ------------- deterministic counting-sort of (token,k) -> expert rows -------------
__global__ void build_index(const int* __restrict__ tk_e, int* __restrict__ tk_row,
                            int* __restrict__ offsets, int* __restrict__ tileE,
                            int* __restrict__ tileRow, int* __restrict__ nTiles) {
  __shared__ int cnt[256][NEXP];
  __shared__ int tot[NEXP];
  __shared__ int off_s[NEXP];
  int t = threadIdx.x;
  int c[NEXP];
#pragma unroll
  for (int e = 0; e < NEXP; e++) c[e] = 0;
  int base = t * 64;
  for (int i = 0; i < 64; i++) {
    int te = tk_e[base + i];
#pragma unroll
    for (int e = 0; e < NEXP; e++) c[e] += (te == e) ? 1 : 0;
  }
#pragma unroll
  for (int e = 0; e < NEXP; e++) cnt[t][e] = c[e];
  __syncthreads();
  if (t < NEXP) {
    int run = 0;
    for (int i = 0; i < 256; i++) { int v = cnt[i][t]; cnt[i][t] = run; run += v; }
    tot[t] = run;
  }
  __syncthreads();
  if (t == 0) {
    int o = 0, tc = 0;
    for (int e = 0; e < NEXP; e++) {
      off_s[e] = o; offsets[e] = o;
      int ce = tot[e];
      for (int i = 0; i < ce; i += 128) { tileE[tc] = e; tileRow[tc] = o + i; tc++; }
      o += ce;
    }
    offsets[NEXP] = o;
    nTiles[0] = tc;
    for (int q = tc; q < MAXT; q++) { tileE[q] = 0; tileRow[q] = 0; }
  }
  __syncthreads();
#pragma unroll
  for (int e = 0; e < NEXP; e++) c[e] = cnt[t][e] + off_s[e];
  for (int i = 0; i < 64; i++) {
    int te = tk_e[base + i];
    int r = 0;
#pragma unroll
    for (int e = 0; e < NEXP; e++) r += (te == e) ? c[e] : 0;
    tk_row[base + i] = r;
#pragma unroll
    for (int e = 0; e < NEXP; e++) c[e] += (te == e) ? 1 : 0;
  }
}

// ------------- gather token rows to bf16 xg; record per-row token/weight -------------
__global__ void build_rows(const float* __restrict__ x, const float* __restrict__ tk_w,
                           const int* __restrict__ tk_row,
                           int* __restrict__ row_token, float* __restrict__ row_w,
                           short* __restrict__ xg) {
  int idx = blockIdx.x;          // 0..NKROW-1 = n*2+k
  int n = idx >> 1;
  int row = tk_row[idx];
  if (threadIdx.x == 0) { row_token[row] = n; row_w[row] = tk_w[idx]; }
  const float4* xr = (const float4*)(x + (size_t)n * DDIM);
  float4 v = xr[threadIdx.x];
  bf16x4 o;
  o[0] = (short)f2bf(v.x); o[1] = (short)f2bf(v.y);
  o[2] = (short)f2bf(v.z); o[3] = (short)f2bf(v.w);
  *(bf16x4*)(xg + (size_t)row * DDIM + threadIdx.x * 4) = o;
}

// ------------- tiled transpose + fp32->bf16: in [R][C] -> out [C][R] per expert -------------
__global__ void transpose_cvt(const float* __restrict__ in, short* __restrict__ out,
                              int R, int C) {
  __shared__ float tile[64][65];
  int e = blockIdx.z;
  int cB = blockIdx.x * 64;
  int rB = blockIdx.y * 64;
  const float* src = in + (size_t)e * R * C;
  short* dst = out + (size_t)e * R * C;
  int t = threadIdx.x;
  int lr = t >> 4;             // 0..15
  int lc = (t & 15) * 4;
#pragma unroll
  for (int i = 0; i < 4; i++) {
    const float* p = src + (size_t)(rB + lr + i * 16) * C + cB + lc;
    float4 v = *(const float4*)p;
    tile[lr + i * 16][lc + 0] = v.x;
    tile[lr + i * 16][lc + 1] = v.y;
    tile[lr + i * 16][lc + 2] = v.z;
    tile[lr + i * 16][lc + 3] = v.w;
  }
  __syncthreads();
  int oc = t >> 2;             // 0..63 : input col -> output row
  int orr = (t & 3) * 16;      // input row chunk -> output cols
  bf16x8 o0, o1;
#pragma unroll
  for (int q = 0; q < 8; q++) {
    o0[q] = (short)f2bf(tile[orr + q][oc]);
    o1[q] = (short)f2bf(tile[orr + 8 + q][oc]);
  }
  short* op = dst + (size_t)(cB + oc) * R + rB + orr;
  *(bf16x8*)op = o0;
  *(bf16x8*)(op + 8) = o1;
}

// ------------- GEMM1: xg[rows,1024] x {wg,wu}[n,k] -> SwiGLU -> h[rows,2048] bf16 -------------
struct SM1U {
  union {
    struct { short A[128 * 32]; short B[128 * 32]; } st;
    float eps[64][132];
  };
};

__global__ __launch_bounds__(256) void gemm1(
    const short* __restrict__ xg, const short* __restrict__ wg, const short* __restrict__ wu,
    const int* __restrict__ tileE, const int* __restrict__ tileRow,
    const int* __restrict__ nTiles, const int* __restrict__ offsets,
    short* __restrict__ h) {
  if ((int)blockIdx.y >= nTiles[0]) return;
  int e = tileE[blockIdx.y];
  int rowBase = tileRow[blockIdx.y];
  int segEnd = offsets[e + 1];
  int fB = blockIdx.x * 64;     // 64 f's; cols 0..63 = gate, 64..127 = up

  __shared__ __align__(16) SM1U sm;

  int tid = threadIdx.x;
  int w = tid >> 6, lane = tid & 63;
  int wr = w >> 1, wc = w & 1;
  int lr = lane >> 2;
  int kp = (lane & 3) * 8;

  const short* gA0 = xg + (size_t)(rowBase + (w * 16 + lr)) * DDIM + kp;
  const short* gA1 = xg + (size_t)(rowBase + ((w + 4) * 16 + lr)) * DDIM + kp;
  int nl0 = w * 16 + lr;             // 0..63  -> gate col fB+nl0
  int nl1 = (w + 4) * 16 + lr;       // 64..127 -> up col fB+nl1-64
  const short* gB0 = wg + ((size_t)e * FDIM + fB + nl0) * DDIM + kp;
  const short* gB1 = wu + ((size_t)e * FDIM + fB + (nl1 - 64)) * DDIM + kp;

  short* sA = sm.st.A;
  short* sB = sm.st.B;
  int sOff0 = w * 512 + lane * 8;
  int sOff1 = (w + 4) * 512 + lane * 8;

  f32x4 acc[4][4];
  f32x4 z = {0.f, 0.f, 0.f, 0.f};
#pragma unroll
  for (int m = 0; m < 4; m++)
#pragma unroll
    for (int n = 0; n < 4; n++) acc[m][n] = z;

  bf16x8 ra0 = *(const bf16x8*)(gA0);
  bf16x8 ra1 = *(const bf16x8*)(gA1);
  bf16x8 rb0 = *(const bf16x8*)(gB0);
  bf16x8 rb1 = *(const bf16x8*)(gB1);

  for (int kk = 0; kk < DDIM; kk += 32) {
    __syncthreads();
    *(bf16x8*)(sA + sOff0) = ra0;
    *(bf16x8*)(sA + sOff1) = ra1;
    *(bf16x8*)(sB + sOff0) = rb0;
    *(bf16x8*)(sB + sOff1) = rb1;
    __syncthreads();
    if (kk + 32 < DDIM) {
      ra0 = *(const bf16x8*)(gA0 + kk + 32);
      ra1 = *(const bf16x8*)(gA1 + kk + 32);
      rb0 = *(const bf16x8*)(gB0 + kk + 32);
      rb1 = *(const bf16x8*)(gB1 + kk + 32);
    }
    bf16x8 af[4], bb[4];
#pragma unroll
    for (int m = 0; m < 4; m++)
      af[m] = *(const bf16x8*)(sA + (wr * 64 + m * 16 + (lane & 15)) * 32 + (lane >> 4) * 8);
#pragma unroll
    for (int n = 0; n < 4; n++)
      bb[n] = *(const bf16x8*)(sB + (wc * 64 + n * 16 + (lane & 15)) * 32 + (lane >> 4) * 8);
#pragma unroll
    for (int m = 0; m < 4; m++)
#pragma unroll
      for (int n = 0; n < 4; n++)
        acc[m][n] = __builtin_amdgcn_mfma_f32_16x16x32_bf16(af[m], bb[n], acc[m][n], 0, 0, 0);
  }

  // SwiGLU epilogue via LDS exchange (half tile at a time; fp32)
#pragma unroll 1
  for (int half = 0; half < 2; half++) {
    __syncthreads();
    if (wr == half) {
#pragma unroll
      for (int m = 0; m < 4; m++)
#pragma unroll
        for (int n = 0; n < 4; n++)
#pragma unroll
          for (int j = 0; j < 4; j++)
            sm.eps[m * 16 + (lane >> 4) * 4 + j][wc * 64 + n * 16 + (lane & 15)] = acc[m][n][j];
    }
    __syncthreads();
    int jj = tid & 63, r0 = tid >> 6;
#pragma unroll 1
    for (int i = 0; i < 16; i++) {
      int r = r0 + i * 4;
      int grow = rowBase + half * 64 + r;
      if (grow < segEnd) {
        float g = sm.eps[r][jj];
        float u = sm.eps[r][64 + jj];
        float hv = g / (1.0f + __expf(-g)) * u;
        h[(size_t)grow * FDIM + fB + jj] = (short)f2bf(hv);
      }
    }
  }
}

// ------------- GEMM2: h[rows,2048] x wb2[d,f] -> y[token] += w * out -------------
__global__ __launch_bounds__(256) void gemm2(
    const short* __restrict__ h, const short* __restrict__ w2,
    const int* __restrict__ tileE, const int* __restrict__ tileRow,
    const int* __restrict__ nTiles, const int* __restrict__ offsets,
    const int* __restrict__ row_token, const float* __restrict__ row_w,
    float* __restrict__ y) {
  if ((int)blockIdx.y >= nTiles[0]) return;
  int e = tileE[blockIdx.y];
  int rowBase = tileRow[blockIdx.y];
  int segEnd = offsets[e + 1];
  int dB = blockIdx.x * 128;

  __shared__ __align__(16) struct { short A[128 * 32]; short B[128 * 32]; } sm;

  int tid = threadIdx.x;
  int w = tid >> 6, lane = tid & 63;
  int wr = w >> 1, wc = w & 1;
  int lr = lane >> 2;
  int kp = (lane & 3) * 8;

  const short* gA0 = h + (size_t)(rowBase + (w * 16 + lr)) * FDIM + kp;
  const short* gA1 = h + (size_t)(rowBase + ((w + 4) * 16 + lr)) * FDIM + kp;
  const short* gB0 = w2 + ((size_t)e * DDIM + dB + (w * 16 + lr)) * FDIM + kp;
  const short* gB1 = w2 + ((size_t)e * DDIM + dB + ((w + 4) * 16 + lr)) * FDIM + kp;

  int sOff0 = w * 512 + lane * 8;
  int sOff1 = (w + 4) * 512 + lane * 8;

  f32x4 acc[4][4];
  f32x4 z = {0.f, 0.f, 0.f, 0.f};
#pragma unroll
  for (int m = 0; m < 4; m++)
#pragma unroll
    for (int n = 0; n < 4; n++) acc[m][n] = z;

  bf16x8 ra0 = *(const bf16x8*)(gA0);
  bf16x8 ra1 = *(const bf16x8*)(gA1);
  bf16x8 rb0 = *(const bf16x8*)(gB0);
  bf16x8 rb1 = *(const bf16x8*)(gB1);

  for (int kk = 0; kk < FDIM; kk += 32) {
    __syncthreads();
    *(bf16x8*)(sm.A + sOff0) = ra0;
    *(bf16x8*)(sm.A + sOff1) = ra1;
    *(bf16x8*)(sm.B + sOff0) = rb0;
    *(bf16x8*)(sm.B + sOff1) = rb1;
    __syncthreads();
    if (kk + 32 < FDIM) {
      ra0 = *(const bf16x8*)(gA0 + kk + 32);
      ra1 = *(const bf16x8*)(gA1 + kk + 32);
      rb0 = *(const bf16x8*)(gB0 + kk + 32);
      rb1 = *(const bf16x8*)(gB1 + kk + 32);
    }
    bf16x8 af[4], bb[4];
#pragma unroll
    for (int m = 0; m < 4; m++)
      af[m] = *(const bf16x8*)(sm.A + (wr * 64 + m * 16 + (lane & 15)) * 32 + (lane >> 4) * 8);
#pragma unroll
    for (int n = 0; n < 4; n++)
      bb[n] = *(const bf16x8*)(sm.B + (wc * 64 + n * 16 + (lane & 15)) * 32 + (lane >> 4) * 8);
#pragma unroll
    for (int m = 0; m < 4; m++)
#pragma unroll
      for (int n = 0; n < 4; n++)
        acc[m][n] = __builtin_amdgcn_mfma_f32_16x16x32_bf16(af[m], bb[n], acc[m][n], 0, 0, 0);
  }

#pragma unroll
  for (int m = 0; m < 4; m++) {
#pragma unroll
    for (int j4 = 0; j4 < 4; j4++) {
      int r = wr * 64 + m * 16 + (lane >> 4) * 4 + j4;
      int grow = rowBase + r;
      if (grow < segEnd) {
        int tok = row_token[grow];
        float wgt = row_w[grow];
        float* yr = y + (size_t)tok * DDIM + dB + wc * 64 + (lane & 15);
#pragma unroll
        for (int n = 0; n < 4; n++)
          atomicAdd(yr + n * 16, wgt * acc[m][n][j4]);
      }
    }
  }
}

extern "C" void kernel_launch(void* const* d_in, const int* in_sizes, int n_in,
                              void* d_out, int out_size, void* d_ws, size_t ws_size,
                              hipStream_t stream) {
  const float* x      = (const float*)d_in[0];
  const float* gw     = (const float*)d_in[1];
  const float* w_gate = (const float*)d_in[2];
  const float* w_up   = (const float*)d_in[3];
  const float* w_down = (const float*)d_in[4];
  float* y = (float*)d_out;
  (void)in_sizes; (void)n_in; (void)ws_size;

  char* ws = (char*)d_ws;
  size_t off = 0;
  auto alloc = [&](size_t bytes) -> void* {
    void* p = ws + off; off += (bytes + 255) & ~(size_t)255; return p;
  };
  short* wb1g      = (short*)alloc((size_t)NEXP * FDIM * DDIM * 2);   // [E][F][D] bf16
  short* wb1u      = (short*)alloc((size_t)NEXP * FDIM * DDIM * 2);   // [E][F][D] bf16
  short* wb2       = (short*)alloc((size_t)NEXP * DDIM * FDIM * 2);   // [E][D][F] bf16
  short* xg        = (short*)alloc((size_t)(NKROW + 128) * DDIM * 2); // gathered rows
  short* hbuf      = (short*)alloc((size_t)(NKROW + 128) * FDIM * 2); // SwiGLU output
  int*   tk_e      = (int*)alloc((size_t)NKROW * 4);
  float* tk_w      = (float*)alloc((size_t)NKROW * 4);
  int*   tk_row    = (int*)alloc((size_t)NKROW * 4);
  int*   row_token = (int*)alloc((size_t)(NKROW + 128) * 4);
  float* row_w     = (float*)alloc((size_t)(NKROW + 128) * 4);
  int*   tileE     = (int*)alloc(MAXT * 4);
  int*   tileRow   = (int*)alloc(MAXT * 4);
  int*   nTiles    = (int*)alloc(256);
  int*   offsets   = (int*)alloc(256);

  hipMemsetAsync(d_out, 0, (size_t)out_size * 4, stream);

  transpose_cvt<<<dim3(FDIM / 64, DDIM / 64, NEXP), 256, 0, stream>>>(w_gate, wb1g, DDIM, FDIM);
  transpose_cvt<<<dim3(FDIM / 64, DDIM / 64, NEXP), 256, 0, stream>>>(w_up,   wb1u, DDIM, FDIM);
  transpose_cvt<<<dim3(DDIM / 64, FDIM / 64, NEXP), 256, 0, stream>>>(w_down, wb2,  FDIM, DDIM);
  gate_kernel<<<NTOK / 4, 256, 0, stream>>>(x, gw, tk_e, tk_w);
  build_index<<<1, 256, 0, stream>>>(tk_e, tk_row, offsets, tileE, tileRow, nTiles);
  build_rows<<<NKROW, 256, 0, stream>>>(x, tk_w, tk_row, row_token, row_w, xg);
  gemm1<<<dim3(FDIM / 64, MAXT), 256, 0, stream>>>(xg, wb1g, wb1u, tileE, tileRow, nTiles, offsets, hbuf);
  gemm2<<<dim3(DDIM / 128, MAXT), 256, 0, stream>>>(hbuf, wb2, tileE, tileRow, nTiles, offsets, row_token, row_w, y);
}

// Round 2
// 460.889 us; speedup vs baseline: 1.1199x; 1.1199x over previous
//
#include <hip/hip_runtime.h>
#include <hip/hip_bf16.h>

#define NTOK 8192
#define DDIM 1024
#define NEXP 8
#define FDIM 2048
#define NKROW (NTOK * 2)   // 16384 expert-rows (top-2)
#define MAXT 136           // max row-tiles: 16384/128 + 8 rounding

typedef __attribute__((ext_vector_type(8))) short bf16x8;
typedef __attribute__((ext_vector_type(4))) short bf16x4;
typedef __attribute__((ext_vector_type(4))) float f32x4;

__device__ __forceinline__ unsigned short f2bf(float f) {
  union { float f; unsigned u; } v; v.f = f;
  unsigned r = v.u + 0x7fffu + ((v.u >> 16) & 1u);   // RNE
  return (unsigned short)(r >> 16);
}

// async global->LDS, 16B per lane; LDS dest must be wave-uniform base (+lane*16 implicit)
__device__ __forceinline__ void gl16(const short* g, short* l) {
  __builtin_amdgcn_global_load_lds(
      (const __attribute__((address_space(1))) void*)g,
      (__attribute__((address_space(3))) void*)l, 16, 0, 0);
}

// ---------------- gate: fp64-accum logits, softmax top-2, renorm ----------------
__global__ void gate_kernel(const float* __restrict__ x, const float* __restrict__ gw,
                            int* __restrict__ tk_e, float* __restrict__ tk_w) {
  int wave = threadIdx.x >> 6, lane = threadIdx.x & 63;
  int n = blockIdx.x * 4 + wave;
  const float* xr = x + (size_t)n * DDIM;
  float xv[16];
#pragma unroll
  for (int i = 0; i < 16; i++) xv[i] = xr[lane + i * 64];
  float lg[NEXP];
#pragma unroll
  for (int e = 0; e < NEXP; e++) {
    const float* gr = gw + e * DDIM;
    double a = 0.0;
#pragma unroll
    for (int i = 0; i < 16; i++) a += (double)xv[i] * (double)gr[lane + i * 64];
#pragma unroll
    for (int s = 32; s > 0; s >>= 1) a += __shfl_xor(a, s, 64);
    lg[e] = (float)a;
  }
  if (lane == 0) {
    int i1 = 0; float b1 = lg[0];
#pragma unroll
    for (int e = 1; e < NEXP; e++) if (lg[e] > b1) { b1 = lg[e]; i1 = e; }
    int i2 = -1; float b2 = -3.4e38f;
#pragma unroll
    for (int e = 0; e < NEXP; e++) if (e != i1 && lg[e] > b2) { b2 = lg[e]; i2 = e; }
    float ex = __expf(b2 - b1);
    float inv = 1.0f / (1.0f + ex);
    tk_e[n * 2 + 0] = i1; tk_w[n * 2 + 0] = inv;
    tk_e[n * 2 + 1] = i2; tk_w[n * 2 + 1] = ex * inv;
  }
}

// ------------- deterministic counting-sort of (token,k) -> expert rows -------------
__global__ void build_index(const int* __restrict__ tk_e, int* __restrict__ tk_row,
                            int* __restrict__ offsets, int* __restrict__ tileE,
                            int* __restrict__ tileRow, int* __restrict__ nTiles) {
  __shared__ int cnt[256][NEXP];
  __shared__ int tot[NEXP];
  __shared__ int off_s[NEXP];
  int t = threadIdx.x;
  int c[NEXP];
#pragma unroll
  for (int e = 0; e < NEXP; e++) c[e] = 0;
  int base = t * 64;
  for (int i = 0; i < 64; i++) {
    int te = tk_e[base + i];
#pragma unroll
    for (int e = 0; e < NEXP; e++) c[e] += (te == e) ? 1 : 0;
  }
#pragma unroll
  for (int e = 0; e < NEXP; e++) cnt[t][e] = c[e];
  __syncthreads();
  if (t < NEXP) {
    int run = 0;
    for (int i = 0; i < 256; i++) { int v = cnt[i][t]; cnt[i][t] = run; run += v; }
    tot[t] = run;
  }
  __syncthreads();
  if (t == 0) {
    int o = 0, tc = 0;
    for (int e = 0; e < NEXP; e++) {
      off_s[e] = o; offsets[e] = o;
      int ce = tot[e];
      for (int i = 0; i < ce; i += 128) { tileE[tc] = e; tileRow[tc] = o + i; tc++; }
      o += ce;
    }
    offsets[NEXP] = o;
    nTiles[0] = tc;
    for (int q = tc; q < MAXT; q++) { tileE[q] = 0; tileRow[q] = 0; }
  }
  __syncthreads();
#pragma unroll
  for (int e = 0; e < NEXP; e++) c[e] = cnt[t][e] + off_s[e];
  for (int i = 0; i < 64; i++) {
    int te = tk_e[base + i];
    int r = 0;
#pragma unroll
    for (int e = 0; e < NEXP; e++) r += (te == e) ? c[e] : 0;
    tk_row[base + i] = r;
#pragma unroll
    for (int e = 0; e < NEXP; e++) c[e] += (te == e) ? 1 : 0;
  }
}

// ------------- gather token rows to bf16 xg; record per-row token/weight -------------
__global__ void build_rows(const float* __restrict__ x, const float* __restrict__ tk_w,
                           const int* __restrict__ tk_row,
                           int* __restrict__ row_token, float* __restrict__ row_w,
                           short* __restrict__ xg) {
  int idx = blockIdx.x;          // 0..NKROW-1 = n*2+k
  int n = idx >> 1;
  int row = tk_row[idx];
  if (threadIdx.x == 0) { row_token[row] = n; row_w[row] = tk_w[idx]; }
  const float4* xr = (const float4*)(x + (size_t)n * DDIM);
  float4 v = xr[threadIdx.x];
  bf16x4 o;
  o[0] = (short)f2bf(v.x); o[1] = (short)f2bf(v.y);
  o[2] = (short)f2bf(v.z); o[3] = (short)f2bf(v.w);
  *(bf16x4*)(xg + (size_t)row * DDIM + threadIdx.x * 4) = o;
}

// ------------- tiled transpose + fp32->bf16: in [R][C] -> out [C][R] per expert -------------
__global__ void transpose_cvt(const float* __restrict__ in, short* __restrict__ out,
                              int R, int C) {
  __shared__ float tile[64][65];
  int e = blockIdx.z;
  int cB = blockIdx.x * 64;
  int rB = blockIdx.y * 64;
  const float* src = in + (size_t)e * R * C;
  short* dst = out + (size_t)e * R * C;
  int t = threadIdx.x;
  int lr = t >> 4;             // 0..15
  int lc = (t & 15) * 4;
#pragma unroll
  for (int i = 0; i < 4; i++) {
    const float* p = src + (size_t)(rB + lr + i * 16) * C + cB + lc;
    float4 v = *(const float4*)p;
    tile[lr + i * 16][lc + 0] = v.x;
    tile[lr + i * 16][lc + 1] = v.y;
    tile[lr + i * 16][lc + 2] = v.z;
    tile[lr + i * 16][lc + 3] = v.w;
  }
  __syncthreads();
  int oc = t >> 2;             // 0..63 : input col -> output row
  int orr = (t & 3) * 16;      // input row chunk -> output cols
  bf16x8 o0, o1;
#pragma unroll
  for (int q = 0; q < 8; q++) {
    o0[q] = (short)f2bf(tile[orr + q][oc]);
    o1[q] = (short)f2bf(tile[orr + 8 + q][oc]);
  }
  short* op = dst + (size_t)(cB + oc) * R + rB + orr;
  *(bf16x8*)op = o0;
  *(bf16x8*)(op + 8) = o1;
}

// ------------- GEMM1: xg[rows,1024] x {wg,wu}[n,k] -> SwiGLU -> h[rows,2048] bf16 -------------
struct SM1U {
  union {
    short st[2][2][128 * 32];   // [buf][A/B][tile]
    float eps[64][132];
  };
};

__global__ __launch_bounds__(256) void gemm1(
    const short* __restrict__ xg, const short* __restrict__ wg, const short* __restrict__ wu,
    const int* __restrict__ tileE, const int* __restrict__ tileRow,
    const int* __restrict__ nTiles, const int* __restrict__ offsets,
    short* __restrict__ h) {
  if ((int)blockIdx.y >= nTiles[0]) return;
  int e = tileE[blockIdx.y];
  int rowBase = tileRow[blockIdx.y];
  int segEnd = offsets[e + 1];
  int fB = blockIdx.x * 64;     // 64 f's; cols 0..63 = gate, 64..127 = up

  __shared__ __align__(16) SM1U sm;

  int tid = threadIdx.x;
  int w = tid >> 6, lane = tid & 63;
  int wr = w >> 1, wc = w & 1;
  int lr = lane >> 2;
  int kp = (lane & 3) * 8;

  const short* gA0 = xg + (size_t)(rowBase + (w * 16 + lr)) * DDIM + kp;
  const short* gA1 = xg + (size_t)(rowBase + ((w + 4) * 16 + lr)) * DDIM + kp;
  int nl0 = w * 16 + lr;             // 0..63  -> gate col fB+nl0
  const short* gB0 = wg + ((size_t)e * FDIM + fB + nl0) * DDIM + kp;
  const short* gB1 = wu + ((size_t)e * FDIM + fB + nl0) * DDIM + kp;  // up col fB+nl0

  // per-wave uniform LDS store bases (DMA adds lane*16B)
  int aOff0 = w * 512, aOff1 = (w + 4) * 512;   // shorts

  f32x4 acc[4][4];
  f32x4 z = {0.f, 0.f, 0.f, 0.f};
#pragma unroll
  for (int m = 0; m < 4; m++)
#pragma unroll
    for (int n = 0; n < 4; n++) acc[m][n] = z;

  const int NT = DDIM / 32;
  // prologue: stage tile 0 into buf 0
  {
    short* sA = sm.st[0][0]; short* sB = sm.st[0][1];
    gl16(gA0, sA + aOff0);
    gl16(gA1, sA + aOff1);
    gl16(gB0, sB + aOff0);
    gl16(gB1, sB + aOff1);
  }
  __syncthreads();

  for (int t = 0; t < NT; ++t) {
    int buf = t & 1;
    if (t + 1 < NT) {
      int kk = (t + 1) * 32;
      short* sA = sm.st[buf ^ 1][0]; short* sB = sm.st[buf ^ 1][1];
      gl16(gA0 + kk, sA + aOff0);
      gl16(gA1 + kk, sA + aOff1);
      gl16(gB0 + kk, sB + aOff0);
      gl16(gB1 + kk, sB + aOff1);
    }
    const short* sA = sm.st[buf][0];
    const short* sB = sm.st[buf][1];
    bf16x8 af[4], bb[4];
#pragma unroll
    for (int m = 0; m < 4; m++)
      af[m] = *(const bf16x8*)(sA + (wr * 64 + m * 16 + (lane & 15)) * 32 + (lane >> 4) * 8);
#pragma unroll
    for (int n = 0; n < 4; n++)
      bb[n] = *(const bf16x8*)(sB + (wc * 64 + n * 16 + (lane & 15)) * 32 + (lane >> 4) * 8);
#pragma unroll
    for (int m = 0; m < 4; m++)
#pragma unroll
      for (int n = 0; n < 4; n++)
        acc[m][n] = __builtin_amdgcn_mfma_f32_16x16x32_bf16(af[m], bb[n], acc[m][n], 0, 0, 0);
    __syncthreads();   // drains vmcnt(0): next buf staged; this buf's reads done
  }

  // SwiGLU epilogue via LDS exchange (half tile at a time; fp32)
#pragma unroll 1
  for (int half = 0; half < 2; half++) {
    __syncthreads();
    if (wr == half) {
#pragma unroll
      for (int m = 0; m < 4; m++)
#pragma unroll
        for (int n = 0; n < 4; n++)
#pragma unroll
          for (int j = 0; j < 4; j++)
            sm.eps[m * 16 + (lane >> 4) * 4 + j][wc * 64 + n * 16 + (lane & 15)] = acc[m][n][j];
    }
    __syncthreads();
    int jj = tid & 63, r0 = tid >> 6;
#pragma unroll 1
    for (int i = 0; i < 16; i++) {
      int r = r0 + i * 4;
      int grow = rowBase + half * 64 + r;
      if (grow < segEnd) {
        float g = sm.eps[r][jj];
        float u = sm.eps[r][64 + jj];
        float hv = g / (1.0f + __expf(-g)) * u;
        h[(size_t)grow * FDIM + fB + jj] = (short)f2bf(hv);
      }
    }
  }
}

// ------------- GEMM2: h[rows,2048] x wb2[d,f] -> y[token] += w * out -------------
__global__ __launch_bounds__(256) void gemm2(
    const short* __restrict__ h, const short* __restrict__ w2,
    const int* __restrict__ tileE, const int* __restrict__ tileRow,
    const int* __restrict__ nTiles, const int* __restrict__ offsets,
    const int* __restrict__ row_token, const float* __restrict__ row_w,
    float* __restrict__ y) {
  if ((int)blockIdx.y >= nTiles[0]) return;
  int e = tileE[blockIdx.y];
  int rowBase = tileRow[blockIdx.y];
  int segEnd = offsets[e + 1];
  int dB = blockIdx.x * 128;

  __shared__ __align__(16) short smst[2][2][128 * 32];

  int tid = threadIdx.x;
  int w = tid >> 6, lane = tid & 63;
  int wr = w >> 1, wc = w & 1;
  int lr = lane >> 2;
  int kp = (lane & 3) * 8;

  const short* gA0 = h + (size_t)(rowBase + (w * 16 + lr)) * FDIM + kp;
  const short* gA1 = h + (size_t)(rowBase + ((w + 4) * 16 + lr)) * FDIM + kp;
  const short* gB0 = w2 + ((size_t)e * DDIM + dB + (w * 16 + lr)) * FDIM + kp;
  const short* gB1 = w2 + ((size_t)e * DDIM + dB + ((w + 4) * 16 + lr)) * FDIM + kp;

  int aOff0 = w * 512, aOff1 = (w + 4) * 512;

  f32x4 acc[4][4];
  f32x4 z = {0.f, 0.f, 0.f, 0.f};
#pragma unroll
  for (int m = 0; m < 4; m++)
#pragma unroll
    for (int n = 0; n < 4; n++) acc[m][n] = z;

  const int NT = FDIM / 32;
  {
    short* sA = smst[0][0]; short* sB = smst[0][1];
    gl16(gA0, sA + aOff0);
    gl16(gA1, sA + aOff1);
    gl16(gB0, sB + aOff0);
    gl16(gB1, sB + aOff1);
  }
  __syncthreads();

  for (int t = 0; t < NT; ++t) {
    int buf = t & 1;
    if (t + 1 < NT) {
      int kk = (t + 1) * 32;
      short* sA = smst[buf ^ 1][0]; short* sB = smst[buf ^ 1][1];
      gl16(gA0 + kk, sA + aOff0);
      gl16(gA1 + kk, sA + aOff1);
      gl16(gB0 + kk, sB + aOff0);
      gl16(gB1 + kk, sB + aOff1);
    }
    const short* sA = smst[buf][0];
    const short* sB = smst[buf][1];
    bf16x8 af[4], bb[4];
#pragma unroll
    for (int m = 0; m < 4; m++)
      af[m] = *(const bf16x8*)(sA + (wr * 64 + m * 16 + (lane & 15)) * 32 + (lane >> 4) * 8);
#pragma unroll
    for (int n = 0; n < 4; n++)
      bb[n] = *(const bf16x8*)(sB + (wc * 64 + n * 16 + (lane & 15)) * 32 + (lane >> 4) * 8);
#pragma unroll
    for (int m = 0; m < 4; m++)
#pragma unroll
      for (int n = 0; n < 4; n++)
        acc[m][n] = __builtin_amdgcn_mfma_f32_16x16x32_bf16(af[m], bb[n], acc[m][n], 0, 0, 0);
    __syncthreads();
  }

#pragma unroll
  for (int m = 0; m < 4; m++) {
#pragma unroll
    for (int j4 = 0; j4 < 4; j4++) {
      int r = wr * 64 + m * 16 + (lane >> 4) * 4 + j4;
      int grow = rowBase + r;
      if (grow < segEnd) {
        int tok = row_token[grow];
        float wgt = row_w[grow];
        float* yr = y + (size_t)tok * DDIM + dB + wc * 64 + (lane & 15);
#pragma unroll
        for (int n = 0; n < 4; n++)
          atomicAdd(yr + n * 16, wgt * acc[m][n][j4]);
      }
    }
  }
}

extern "C" void kernel_launch(void* const* d_in, const int* in_sizes, int n_in,
                              void* d_out, int out_size, void* d_ws, size_t ws_size,
                              hipStream_t stream) {
  const float* x      = (const float*)d_in[0];
  const float* gw     = (const float*)d_in[1];
  const float* w_gate = (const float*)d_in[2];
  const float* w_up   = (const float*)d_in[3];
  const float* w_down = (const float*)d_in[4];
  float* y = (float*)d_out;
  (void)in_sizes; (void)n_in; (void)ws_size;

  char* ws = (char*)d_ws;
  size_t off = 0;
  auto alloc = [&](size_t bytes) -> void* {
    void* p = ws + off; off += (bytes + 255) & ~(size_t)255; return p;
  };
  short* wb1g      = (short*)alloc((size_t)NEXP * FDIM * DDIM * 2);   // [E][F][D] bf16
  short* wb1u      = (short*)alloc((size_t)NEXP * FDIM * DDIM * 2);   // [E][F][D] bf16
  short* wb2       = (short*)alloc((size_t)NEXP * DDIM * FDIM * 2);   // [E][D][F] bf16
  short* xg        = (short*)alloc((size_t)(NKROW + 128) * DDIM * 2); // gathered rows
  short* hbuf      = (short*)alloc((size_t)(NKROW + 128) * FDIM * 2); // SwiGLU output
  int*   tk_e      = (int*)alloc((size_t)NKROW * 4);
  float* tk_w      = (float*)alloc((size_t)NKROW * 4);
  int*   tk_row    = (int*)alloc((size_t)NKROW * 4);
  int*   row_token = (int*)alloc((size_t)(NKROW + 128) * 4);
  float* row_w     = (float*)alloc((size_t)(NKROW + 128) * 4);
  int*   tileE     = (int*)alloc(MAXT * 4);
  int*   tileRow   = (int*)alloc(MAXT * 4);
  int*   nTiles    = (int*)alloc(256);
  int*   offsets   = (int*)alloc(256);

  hipMemsetAsync(d_out, 0, (size_t)out_size * 4, stream);

  transpose_cvt<<<dim3(FDIM / 64, DDIM / 64, NEXP), 256, 0, stream>>>(w_gate, wb1g, DDIM, FDIM);
  transpose_cvt<<<dim3(FDIM / 64, DDIM / 64, NEXP), 256, 0, stream>>>(w_up,   wb1u, DDIM, FDIM);
  transpose_cvt<<<dim3(DDIM / 64, FDIM / 64, NEXP), 256, 0, stream>>>(w_down, wb2,  FDIM, DDIM);
  gate_kernel<<<NTOK / 4, 256, 0, stream>>>(x, gw, tk_e, tk_w);
  build_index<<<1, 256, 0, stream>>>(tk_e, tk_row, offsets, tileE, tileRow, nTiles);
  build_rows<<<NKROW, 256, 0, stream>>>(x, tk_w, tk_row, row_token, row_w, xg);
  gemm1<<<dim3(FDIM / 64, MAXT), 256, 0, stream>>>(xg, wb1g, wb1u, tileE, tileRow, nTiles, offsets, hbuf);
  gemm2<<<dim3(DDIM / 128, MAXT), 256, 0, stream>>>(hbuf, wb2, tileE, tileRow, nTiles, offsets, row_token, row_w, y);
}